// Round 1
// 603.322 us; speedup vs baseline: 1.0274x; 1.0274x over previous
//
#include <hip/hip_runtime.h>
#include <hip/hip_bf16.h>

// Problem constants (B=64, T=1000, IN=OUT=512)
//   outputs  zs     [64,1000,512]        -> d_out[0 .. 32768000)
//   states   v_full [64,1001,512]        -> d_out[32768000 .. 65568768)
//   states   z_full [64,1001,512]        -> d_out[65568768 .. 98369536)
#define SV_OFF 32768000
#define SZ_OFF 65568768
#define TC 125   // timesteps per chunk
#define NC 8     // chunks (TC*NC = 1000)

typedef __attribute__((ext_vector_type(8))) short bf16x8;
typedef __attribute__((ext_vector_type(4))) float f32x4;

__device__ __forceinline__ unsigned short f2bf(float f) {
  union { float f; unsigned u; } x; x.f = f;
  unsigned r = x.u + 0x7fffu + ((x.u >> 16) & 1u);  // RNE
  return (unsigned short)(r >> 16);
}

__device__ __forceinline__ void gl_lds16(const void* g, void* l) {
  __builtin_amdgcn_global_load_lds(
      (const __attribute__((address_space(1))) unsigned int*)g,
      (__attribute__((address_space(3))) unsigned int*)l, 16, 0, 0);
}

// ---------------------------------------------------------------- prep
__global__ __launch_bounds__(256) void prep(const float* __restrict__ W,
                                            const float* __restrict__ R,
                                            unsigned short* __restrict__ Wb,
                                            float* __restrict__ RT,
                                            int* __restrict__ flags) {
  const int idx = blockIdx.x * 256 + threadIdx.x;
  if (idx < 512 * 512) {
    Wb[idx] = f2bf(W[idx]);
    const int j = idx >> 9;       // RT[j][o] = R[o][j]
    const int o = idx & 511;
    RT[idx] = R[o * 512 + j];
  }
  if (idx < 64) flags[idx] = 0;
}

// ---------------------------------------------------------------- cvt_x
// One-shot f32 -> bf16 conversion of x: 32,768,000 elems, 8 per thread.
__global__ __launch_bounds__(256) void cvt_x(const float* __restrict__ x,
                                             unsigned short* __restrict__ xb) {
  const size_t i = ((size_t)blockIdx.x * 256 + threadIdx.x) * 8;
  const float4 a = *(const float4*)(x + i);
  const float4 b = *(const float4*)(x + i + 4);
  bf16x8 h;
  h[0] = (short)f2bf(a.x); h[1] = (short)f2bf(a.y);
  h[2] = (short)f2bf(a.z); h[3] = (short)f2bf(a.w);
  h[4] = (short)f2bf(b.x); h[5] = (short)f2bf(b.y);
  h[6] = (short)f2bf(b.z); h[7] = (short)f2bf(b.w);
  *(bf16x8*)(xb + i) = h;
}

// ---------------------------------------------------------------- GEMM
// cur[m][n] = sum_k xb[m][k] * Wb[n][k] + bias[n], bf16 MFMA 16x16x32.
// m97 structure: both operands staged via global_load_lds width-16.
__global__ __launch_bounds__(256, 2) void gemm_cur(
    const unsigned short* __restrict__ Ab,  // xb [64000,512] bf16
    const unsigned short* __restrict__ Wb,  // [512,512] bf16
    const float* __restrict__ bias,
    float* __restrict__ C) {                // cur [64000,512] f32
  __shared__ unsigned short As[128][32];
  __shared__ unsigned short Bs[128][32];
  const int tid = threadIdx.x;
  const int bn = blockIdx.x * 128;
  const int bm = blockIdx.y * 128;
  const int wave = tid >> 6;
  const int lane = tid & 63;
  const int lr = lane & 15;
  const int lq = lane >> 4;
  const int mh = (wave & 1) * 64;
  const int nh = (wave >> 1) * 64;

  f32x4 acc[4][4] = {};

  const int lo0 = tid * 16;          // LDS byte offset this thread stages
  const int row0 = lo0 >> 6;         // 0..63 (64B per LDS row of 32 bf16)
  const int colb = lo0 & 63;         // byte offset within the 64B k-slice
  const size_t abase = (size_t)(bm + row0) * 1024 + colb;  // bytes into Ab
  const size_t bbase = (size_t)(bn + row0) * 1024 + colb;  // bytes into Wb

  for (int kk = 0; kk < 16; ++kk) {
    const size_t koff = (size_t)kk * 64;   // 32 bf16 = 64 bytes per K-step
    __syncthreads();
    gl_lds16((const char*)Ab + abase + koff,            (char*)(&As[0][0]) + lo0);
    gl_lds16((const char*)Ab + abase + 65536 + koff,    (char*)(&As[0][0]) + lo0 + 4096);
    gl_lds16((const char*)Wb + bbase + koff,            (char*)(&Bs[0][0]) + lo0);
    gl_lds16((const char*)Wb + bbase + 65536 + koff,    (char*)(&Bs[0][0]) + lo0 + 4096);
    __syncthreads();
    bf16x8 af[4], bfr[4];
#pragma unroll
    for (int i = 0; i < 4; ++i)
      af[i] = *(const bf16x8*)(&As[mh + i * 16 + lr][lq * 8]);
#pragma unroll
    for (int j = 0; j < 4; ++j)
      bfr[j] = *(const bf16x8*)(&Bs[nh + j * 16 + lr][lq * 8]);
#pragma unroll
    for (int i = 0; i < 4; ++i)
#pragma unroll
      for (int j = 0; j < 4; ++j)
        acc[i][j] = __builtin_amdgcn_mfma_f32_16x16x32_bf16(af[i], bfr[j], acc[i][j], 0, 0, 0);
  }
#pragma unroll
  for (int j = 0; j < 4; ++j) {
    const int col = bn + nh + j * 16 + lr;
    const float bv = bias[col];
#pragma unroll
    for (int i = 0; i < 4; ++i) {
      const int r0 = bm + mh + i * 16 + lq * 4;
#pragma unroll
      for (int r = 0; r < 4; ++r)
        C[(size_t)(r0 + r) * 512 + col] = acc[i][j][r] + bv;
    }
  }
}

// ---------------------------------------------------------------- phase 1
// Chunk-local Horner sums: S[b][j][o] = scan of chunk j from v=0 (exact in-chunk
// fp32 op order of the reference). One thread per (b, j, o): 262144 threads.
__global__ __launch_bounds__(256) void chunk_sums(const float* __restrict__ cur,
                                                  const float* __restrict__ decay,
                                                  float* __restrict__ S) {
  const int gt = blockIdx.x * 256 + threadIdx.x;
  const int o = gt & 511;
  const int j = (gt >> 9) & (NC - 1);
  const int b = gt >> 12;
  const float d = decay[o];
  const float om = 1.0f - d;
  const size_t base = (size_t)b * 512000 + (size_t)(j * TC) * 512 + o;
  float nb[8];
#pragma unroll
  for (int u = 0; u < 8; ++u) nb[u] = cur[base + (size_t)u * 512];
  float s = 0.f;
#pragma unroll 8
  for (int k = 0; k < TC; ++k) {
    const float c = nb[k & 7];
    if (k < TC - 8) nb[k & 7] = cur[base + (size_t)(k + 8) * 512];
    s = d * s + om * c;
  }
  S[gt] = s;
}

// ---------------------------------------------------------------- phase 2+3
// In-chunk scan; chunk-start v computed inline from S (same op order as the
// old chunk_prefix: v=0; for jj<j: v = d^TC * v + S[jj]). Writes zs, v_full,
// z_full; flags spikes.
__global__ __launch_bounds__(256) void chunk_scan(const float* __restrict__ cur,
                                                  const float* __restrict__ decay,
                                                  const float* __restrict__ S,
                                                  float* __restrict__ out,
                                                  int* __restrict__ flags) {
  const int gt = blockIdx.x * 256 + threadIdx.x;
  const int o = gt & 511;
  const int j = (gt >> 9) & (NC - 1);
  const int b = gt >> 12;
  const float d = decay[o];
  const float om = 1.0f - d;
  const size_t ci = (size_t)b * 512000 + (size_t)(j * TC) * 512 + o;
  const size_t svb = (size_t)b * 512512 + (size_t)(j * TC) * 512 + o;
  float* __restrict__ sv = out + SV_OFF;
  float* __restrict__ sz = out + SZ_OFF;
  if (j == 0) {  // t=0 state rows
    __builtin_nontemporal_store(0.f, &sv[svb]);
    __builtin_nontemporal_store(0.f, &sz[svb]);
  }
  // inline chunk-start prefix (identical arithmetic to old chunk_prefix)
  float v = 0.f;
  if (j > 0) {
    const float dTC = powf(d, (float)TC);
    const int sb = (b << 12) + o;
    for (int jj = 0; jj < j; ++jj) v = dTC * v + S[sb + (jj << 9)];
  }
  int fl = 0;
  float nb[8];
#pragma unroll
  for (int u = 0; u < 8; ++u) nb[u] = cur[ci + (size_t)u * 512];
#pragma unroll 8
  for (int k = 0; k < TC; ++k) {
    const float c = nb[k & 7];
    if (k < TC - 8) nb[k & 7] = cur[ci + (size_t)(k + 8) * 512];
    v = d * v + om * c;  // (1-z)=1 multiply is exact in the no-spike path
    const float z = (v >= 1.0f) ? 1.0f : 0.0f;
    fl |= (v >= 1.0f);
    const size_t row = (size_t)k * 512;
    __builtin_nontemporal_store(z, &out[ci + row]);
    __builtin_nontemporal_store(v, &sv[svb + row + 512]);
    __builtin_nontemporal_store(z, &sz[svb + row + 512]);
  }
  if (fl) atomicOr(flags + b, 1);
}

// ---------------------------------------------------------------- fixup (rare path)
__global__ __launch_bounds__(512) void scan_fix(const float* __restrict__ cur,
                                                const float* __restrict__ decay,
                                                const float* __restrict__ RT,
                                                float* __restrict__ out,
                                                const int* __restrict__ flags) {
  const int b = blockIdx.x;
  if (flags[b] == 0) return;
  const int o = threadIdx.x;
  __shared__ int cnt;
  __shared__ int list[512];
  const float d = decay[o];
  const float om = 1.f - d;
  float v = 0.f, z = 0.f;
  const size_t ci = (size_t)b * 512000 + o;
  const size_t svb = (size_t)b * 512512 + o;
  float* __restrict__ sv = out + SV_OFF;
  float* __restrict__ sz = out + SZ_OFF;
  sv[svb] = 0.f;
  sz[svb] = 0.f;
  if (o == 0) cnt = 0;
  __syncthreads();
  for (int t = 0; t < 1000; ++t) {
    float soma = cur[ci + (size_t)t * 512];
    const int n = cnt;
    for (int i = 0; i < n; ++i) soma += RT[(size_t)list[i] * 512 + o];
    v = d * (v * (1.f - z)) + om * soma;
    z = (v >= 1.0f) ? 1.0f : 0.0f;
    out[ci + (size_t)t * 512] = z;
    sv[svb + (size_t)(t + 1) * 512] = v;
    sz[svb + (size_t)(t + 1) * 512] = z;
    __syncthreads();
    if (o == 0) cnt = 0;
    __syncthreads();
    if (z != 0.f) { const int p = atomicAdd(&cnt, 1); list[p] = o; }
    __syncthreads();
  }
}

extern "C" void kernel_launch(void* const* d_in, const int* in_sizes, int n_in,
                              void* d_out, int out_size, void* d_ws, size_t ws_size,
                              hipStream_t stream) {
  (void)in_sizes; (void)n_in; (void)out_size; (void)ws_size;
  const float* x     = (const float*)d_in[0];  // [64,1000,512]
  const float* W     = (const float*)d_in[1];  // [512,512]
  const float* bias  = (const float*)d_in[2];  // [512]
  const float* R     = (const float*)d_in[3];  // [512,512]
  const float* decay = (const float*)d_in[4];  // [512]
  float* out = (float*)d_out;

  char* ws = (char*)d_ws;
  float* cur          = (float*)ws;                        // 131,072,000 B
  unsigned short* Wb  = (unsigned short*)(ws + 131072000); //     524,288 B
  float* RT           = (float*)(ws + 131596288);          //   1,048,576 B
  int* flags          = (int*)(ws + 132644864);            //       4,096 B
  float* S            = (float*)(ws + 132648960);          //   1,048,576 B
  // total ws use: 133,697,536 B (smaller than before; Vs eliminated)

  // xb lives in the v_full output region: chunk_scan overwrites it only
  // AFTER gemm_cur has consumed it (stream-ordered). Zero extra workspace.
  unsigned short* xb = (unsigned short*)(out + SV_OFF);    // 65,536,000 B

  prep<<<1024, 256, 0, stream>>>(W, R, Wb, RT, flags);
  cvt_x<<<16000, 256, 0, stream>>>(x, xb);
  gemm_cur<<<dim3(4, 500), 256, 0, stream>>>(xb, Wb, bias, cur);
  chunk_sums<<<1024, 256, 0, stream>>>(cur, decay, S);
  chunk_scan<<<1024, 256, 0, stream>>>(cur, decay, S, out, flags);
  scan_fix<<<64, 512, 0, stream>>>(cur, decay, RT, out, flags);
}

// Round 2
// 547.555 us; speedup vs baseline: 1.1321x; 1.1018x over previous
//
#include <hip/hip_runtime.h>

// Problem constants (B=64, T=1000, IN=OUT=512)
//   outputs  zs     [64,1000,512]        -> d_out[0 .. 32768000)
//   states   v_full [64,1001,512]        -> d_out[32768000 .. 65568768)
//   states   z_full [64,1001,512]        -> d_out[65568768 .. 98369536)
#define SV_OFF 32768000
#define SZ_OFF 65568768

typedef __attribute__((ext_vector_type(8))) short bf16x8;
typedef __attribute__((ext_vector_type(4))) float f32x4;

__device__ __forceinline__ unsigned short f2bf(float f) {
  union { float f; unsigned u; } x; x.f = f;
  unsigned r = x.u + 0x7fffu + ((x.u >> 16) & 1u);  // RNE
  return (unsigned short)(r >> 16);
}

__device__ __forceinline__ void gl_lds16(const void* g, void* l) {
  __builtin_amdgcn_global_load_lds(
      (const __attribute__((address_space(1))) unsigned int*)g,
      (__attribute__((address_space(3))) unsigned int*)l, 16, 0, 0);
}

// ---------------------------------------------------------------- prep
__global__ __launch_bounds__(256) void prep(const float* __restrict__ W,
                                            unsigned short* __restrict__ Wb,
                                            int* __restrict__ flags) {
  const int idx = blockIdx.x * 256 + threadIdx.x;
  if (idx < 512 * 512) Wb[idx] = f2bf(W[idx]);
  if (idx < 64) flags[idx] = 0;
}

// ---------------------------------------------------------------- cvt_x
// One-shot f32 -> bf16 conversion of x: 32,768,000 elems, 8 per thread.
__global__ __launch_bounds__(256) void cvt_x(const float* __restrict__ x,
                                             unsigned short* __restrict__ xb) {
  const size_t i = ((size_t)blockIdx.x * 256 + threadIdx.x) * 8;
  const float4 a = *(const float4*)(x + i);
  const float4 b = *(const float4*)(x + i + 4);
  bf16x8 h;
  h[0] = (short)f2bf(a.x); h[1] = (short)f2bf(a.y);
  h[2] = (short)f2bf(a.z); h[3] = (short)f2bf(a.w);
  h[4] = (short)f2bf(b.x); h[5] = (short)f2bf(b.y);
  h[6] = (short)f2bf(b.z); h[7] = (short)f2bf(b.w);
  *(bf16x8*)(xb + i) = h;
}

// ---------------------------------------------------------------- fused GEMM+scan
// Persistent block per (b, 64-wide o-slice). Per 128-t tile: MFMA GEMM
// (cur tile kept in LDS, never in HBM) then exact sequential scan.
// Grid dim3(64,8): all 8 o-slices of batch b land on XCD b%8 (id%8 model),
// so x[b] is fetched from HBM once and reused via that XCD's L2.
__global__ __launch_bounds__(256, 2) void fused(
    const unsigned short* __restrict__ Ab,   // xb [64000,512] bf16
    const unsigned short* __restrict__ Wb,   // [512,512] bf16
    const float* __restrict__ bias,
    const float* __restrict__ decay,
    float* __restrict__ out,
    int* __restrict__ flags) {
  __shared__ unsigned short As[2][128][32];  // 16 KB (A k-step dbuf)
  __shared__ unsigned short Bs[2][64][32];   //  8 KB (B k-step dbuf)
  __shared__ float cs[128][64];              // 32 KB (cur tile, swizzled)

  const int b    = blockIdx.x;
  const int o0   = blockIdx.y * 64;
  const int tid  = threadIdx.x;
  const int wave = tid >> 6;
  const int lane = tid & 63;
  const int lr = lane & 15;
  const int lq = lane >> 4;
  const int wr = wave >> 1;   // t-half of tile (0..1)
  const int wc = wave & 1;    // o-half of slice (0..1)

  // staging geometry: 256 threads x 16 B, lane-linear LDS dest
  const int arow = tid >> 2;          // 0..63
  const int acb  = (tid & 3) * 16;    // byte within 64B k-slice
  const char* abase = (const char*)Ab + (size_t)b * 1000 * 1024;
  const char* bbase = (const char*)Wb + (size_t)o0 * 1024;

#define STAGE(pp, t0s, kks) do {                                                   \
    const int _kb = (kks) * 64 + acb;                                              \
    gl_lds16(abase + (size_t)((t0s) + arow) * 1024 + _kb,                          \
             (char*)&As[pp][0][0] + tid * 16);                                     \
    gl_lds16(abase + (size_t)((t0s) + 64 + arow) * 1024 + _kb,                     \
             (char*)&As[pp][0][0] + tid * 16 + 4096);                              \
    gl_lds16(bbase + (size_t)arow * 1024 + _kb,                                    \
             (char*)&Bs[pp][0][0] + tid * 16);                                     \
  } while (0)

  // scan state (threads 0..63 own one o each; v carried across tiles)
  float v = 0.f, d = 0.f, om = 0.f, bv = 0.f;
  int fl = 0;
  if (tid < 64) {
    d  = decay[o0 + tid];
    om = 1.f - d;
    bv = bias[o0 + tid];
    // t=0 state rows
    __builtin_nontemporal_store(0.f, out + SV_OFF + (size_t)b * 512512 + o0 + tid);
    __builtin_nontemporal_store(0.f, out + SZ_OFF + (size_t)b * 512512 + o0 + tid);
  }

  int p = 0;
  STAGE(0, 0, 0);
  for (int tile = 0; tile < 8; ++tile) {
    const int t0 = tile * 128;
    f32x4 acc[4][2] = {};
    for (int kk = 0; kk < 16; ++kk) {
      __syncthreads();                     // buf[p] staged (vmcnt drained)
      if (kk < 15)       STAGE(p ^ 1, t0, kk + 1);        // prefetch next k-step
      else if (tile < 7) STAGE(p ^ 1, t0 + 128, 0);       // prefetch next tile
      bf16x8 af[4], bf[2];
#pragma unroll
      for (int i = 0; i < 4; ++i)
        af[i] = *(const bf16x8*)(&As[p][wr * 64 + i * 16 + lr][lq * 8]);
#pragma unroll
      for (int j = 0; j < 2; ++j)
        bf[j] = *(const bf16x8*)(&Bs[p][wc * 32 + j * 16 + lr][lq * 8]);
#pragma unroll
      for (int i = 0; i < 4; ++i)
#pragma unroll
        for (int j = 0; j < 2; ++j)
          acc[i][j] = __builtin_amdgcn_mfma_f32_16x16x32_bf16(af[i], bf[j], acc[i][j], 0, 0, 0);
      p ^= 1;
    }
    // acc -> cur LDS tile. Swizzle col by lq bit0 so both this write (2-way)
    // and the scan read (2-way) stay bank-conflict-free.
#pragma unroll
    for (int i = 0; i < 4; ++i)
#pragma unroll
      for (int j = 0; j < 2; ++j) {
        const int tb = wr * 64 + i * 16 + lq * 4;
        const int cc = (wc * 32 + j * 16 + lr) ^ ((lq & 1) << 4);
#pragma unroll
        for (int r = 0; r < 4; ++r) cs[tb + r][cc] = acc[i][j][r];
      }
    __syncthreads();                       // cur tile visible to wave 0
    if (tid < 64) {
      const int tmax = (tile == 7) ? 104 : 128;   // 1000 = 7*128 + 104
      float* zp = out + ((size_t)b * 1000 + t0) * 512 + o0 + tid;
      float* vp = out + SV_OFF + ((size_t)b * 1001 + t0 + 1) * 512 + o0 + tid;
      float* sp = out + SZ_OFF + ((size_t)b * 1001 + t0 + 1) * 512 + o0 + tid;
      for (int t = 0; t < tmax; t += 4) {
        const int cc = tid ^ (((t >> 2) & 1) << 4);
        float c4[4];
#pragma unroll
        for (int u = 0; u < 4; ++u) c4[u] = cs[t + u][cc];
#pragma unroll
        for (int u = 0; u < 4; ++u) {
          v = d * v + om * (c4[u] + bv);   // exact reference op order (no-spike path)
          const float z = (v >= 1.0f) ? 1.0f : 0.0f;
          fl |= (v >= 1.0f);
          __builtin_nontemporal_store(z, zp + (size_t)(t + u) * 512);
          __builtin_nontemporal_store(v, vp + (size_t)(t + u) * 512);
          __builtin_nontemporal_store(z, sp + (size_t)(t + u) * 512);
        }
      }
    }
    // no barrier here: next tile's first k-step barrier orders scan vs staging
  }
  if (tid < 64 && fl) atomicOr(flags + b, 1);
#undef STAGE
}

// ---------------------------------------------------------------- fixup (rare path)
// Self-sufficient: recomputes soma via f32 GEMV (cur is never materialized).
// Only runs when a batch actually spiked on the speculative path (never here).
__global__ __launch_bounds__(512) void scan_fix(const float* __restrict__ x,
                                                const float* __restrict__ W,
                                                const float* __restrict__ bias,
                                                const float* __restrict__ R,
                                                const float* __restrict__ decay,
                                                float* __restrict__ out,
                                                const int* __restrict__ flags) {
  const int b = blockIdx.x;
  if (flags[b] == 0) return;
  const int o = threadIdx.x;
  __shared__ float xs[512];
  __shared__ int cnt;
  __shared__ int list[512];
  const float d = decay[o];
  const float om = 1.f - d;
  float v = 0.f, z = 0.f;
  const size_t zb  = (size_t)b * 512000 + o;
  const size_t svb = (size_t)b * 512512 + o;
  float* __restrict__ sv = out + SV_OFF;
  float* __restrict__ sz = out + SZ_OFF;
  sv[svb] = 0.f;
  sz[svb] = 0.f;
  if (o == 0) cnt = 0;
  __syncthreads();
  for (int t = 0; t < 1000; ++t) {
    xs[o] = x[((size_t)b * 1000 + t) * 512 + o];
    __syncthreads();
    float soma = bias[o];
    for (int i = 0; i < 512; ++i) soma += xs[i] * W[(size_t)o * 512 + i];
    const int n = cnt;
    for (int i = 0; i < n; ++i) soma += R[(size_t)o * 512 + list[i]];
    v = d * (v * (1.f - z)) + om * soma;
    z = (v >= 1.0f) ? 1.0f : 0.0f;
    out[zb + (size_t)t * 512] = z;
    sv[svb + (size_t)(t + 1) * 512] = v;
    sz[svb + (size_t)(t + 1) * 512] = z;
    __syncthreads();
    if (o == 0) cnt = 0;
    __syncthreads();
    if (z != 0.f) { const int q = atomicAdd(&cnt, 1); list[q] = o; }
    __syncthreads();
  }
}

extern "C" void kernel_launch(void* const* d_in, const int* in_sizes, int n_in,
                              void* d_out, int out_size, void* d_ws, size_t ws_size,
                              hipStream_t stream) {
  (void)in_sizes; (void)n_in; (void)out_size; (void)ws_size;
  const float* x     = (const float*)d_in[0];  // [64,1000,512]
  const float* W     = (const float*)d_in[1];  // [512,512]
  const float* bias  = (const float*)d_in[2];  // [512]
  const float* R     = (const float*)d_in[3];  // [512,512]
  const float* decay = (const float*)d_in[4];  // [512]
  float* out = (float*)d_out;

  char* ws = (char*)d_ws;
  unsigned short* xb = (unsigned short*)ws;                 // 65,536,000 B
  unsigned short* Wb = (unsigned short*)(ws + 65536000);    //    524,288 B
  int* flags         = (int*)(ws + 66060288);               //        256 B
  // (OOB-safe: last block's padded tile reads spill only into Wb region)

  prep<<<1024, 256, 0, stream>>>(W, Wb, flags);
  cvt_x<<<16000, 256, 0, stream>>>(x, xb);
  fused<<<dim3(64, 8), 256, 0, stream>>>(xb, Wb, bias, decay, out, flags);
  scan_fix<<<64, 512, 0, stream>>>(x, W, bias, R, decay, out, flags);
}